// Round 15
// baseline (287.801 us; speedup 1.0000x reference)
//
#include <hip/hip_runtime.h>
#include <hip/hip_bf16.h>
#include <math.h>

#define D_MODEL 768
#define NH 12
#define HD 64
#define BATCH 2
#define SEQ 4096
#define NROWS (BATCH * SEQ)   // 8192

#define QSCALE 0.18033688011112042f   // 0.125 * log2(e): softmax via exp2

typedef __attribute__((ext_vector_type(8))) short short8;
typedef __attribute__((ext_vector_type(4))) short short4v;
typedef __attribute__((ext_vector_type(4))) float f32x4;
typedef __attribute__((ext_vector_type(16))) float f32x16;
typedef __attribute__((ext_vector_type(4))) unsigned int uint4v;

__device__ inline unsigned short f2bf(float f) {
    __hip_bfloat16 h = __float2bfloat16(f);   // RNE
    return *reinterpret_cast<unsigned short*>(&h);
}

// packed f32x2 -> bf16x2 (RNE), one VALU op
__device__ __forceinline__ unsigned int cvtpk_bf16(float lo, float hi) {
    unsigned int d;
    asm("v_cvt_pk_bf16_f32 %0, %1, %2" : "=v"(d) : "v"(lo), "v"(hi));
    return d;
}

__device__ __forceinline__ short8 u4_as_s8(uint4v u) {
    return *reinterpret_cast<short8*>(&u);
}

// async global->LDS DMA, 16 B per lane; LDS dest is wave-uniform base + lane*16
__device__ __forceinline__ void async_ld16(const unsigned short* g, unsigned short* l) {
    __builtin_amdgcn_global_load_lds(
        (const __attribute__((address_space(1))) void*)g,
        (__attribute__((address_space(3))) void*)l, 16, 0, 0);
}

// ---------------------------------------------------------------------------
// x fp32 -> bf16 (same layout). 8 elems/thread.
// ---------------------------------------------------------------------------
__global__ __launch_bounds__(256) void convert_x_k(
    const float* __restrict__ x, unsigned short* __restrict__ xb)
{
    size_t i = ((size_t)blockIdx.x * 256 + threadIdx.x) * 8;
    float4 a = *(const float4*)(x + i);
    float4 b = *(const float4*)(x + i + 4);
    short8 o;
    o[0] = (short)f2bf(a.x); o[1] = (short)f2bf(a.y);
    o[2] = (short)f2bf(a.z); o[3] = (short)f2bf(a.w);
    o[4] = (short)f2bf(b.x); o[5] = (short)f2bf(b.y);
    o[6] = (short)f2bf(b.z); o[7] = (short)f2bf(b.w);
    *(short8*)(xb + i) = o;
}

// ---------------------------------------------------------------------------
// W fp32 [768][768] -> Wt bf16 [768][768] TRANSPOSED (Wt[n][k] = W[k][n]).
// ---------------------------------------------------------------------------
__global__ __launch_bounds__(256) void convert_wt_k(
    const float* __restrict__ Wq, const float* __restrict__ Wk,
    const float* __restrict__ Wv, const float* __restrict__ Wo,
    unsigned short* __restrict__ wt)
{
    const float* W = (blockIdx.z == 0) ? Wq : (blockIdx.z == 1) ? Wk
                   : (blockIdx.z == 2) ? Wv : Wo;
    unsigned short* dst = wt + (size_t)blockIdx.z * D_MODEL * D_MODEL;
    __shared__ float tile[64][65];
    const int k0 = blockIdx.x * 64, n0 = blockIdx.y * 64;
    const int t = threadIdx.x;
    const int r = t >> 2, seg = t & 3;
    const float* src = W + (size_t)(k0 + r) * D_MODEL + n0 + seg * 16;
    #pragma unroll
    for (int i = 0; i < 4; ++i) {
        float4 v = *(const float4*)(src + i * 4);
        tile[r][seg * 16 + i * 4 + 0] = v.x;
        tile[r][seg * 16 + i * 4 + 1] = v.y;
        tile[r][seg * 16 + i * 4 + 2] = v.z;
        tile[r][seg * 16 + i * 4 + 3] = v.w;
    }
    __syncthreads();
    unsigned short* d = dst + (size_t)(n0 + r) * D_MODEL + k0 + seg * 16;
    short8 o0, o1;
    #pragma unroll
    for (int j = 0; j < 8; ++j) o0[j] = (short)f2bf(tile[seg * 16 + j][r]);
    #pragma unroll
    for (int j = 0; j < 8; ++j) o1[j] = (short)f2bf(tile[seg * 16 + 8 + j][r]);
    *(short8*)(d) = o0;
    *(short8*)(d + 8) = o1;
}

// ---------------------------------------------------------------------------
// FUSED QKV projection (R7 structure). K and V^T written in FRAG-TILED
// layouts so flash can stage/read MFMA fragments as linear 16B-per-lane
// chunks (also much better write coalescing for V^T — R10 measured win):
//   K tiled:  idx = bh*S*HD + T*4096 + kti*2048 + ks*512 + lane*8 + j
//   V tiled:  idx = bh*S*HD + T*4096 + dt*2048 + ks*512 + lane*8 + j
// ---------------------------------------------------------------------------
__global__ __launch_bounds__(256, 3) void qkv_fused_k(
    const unsigned short* __restrict__ xb,
    const unsigned short* __restrict__ wt,   // [3][768][768] (q,k,v transposed)
    const float* __restrict__ bq, const float* __restrict__ bk,
    const float* __restrict__ bv,
    unsigned short* __restrict__ qb,         // [B,H,S,64] (pre-scaled)
    unsigned short* __restrict__ kb,         // frag-tiled (see above)
    unsigned short* __restrict__ vtb)        // frag-tiled (see above)
{
    __shared__ unsigned short As[128][64];
    __shared__ unsigned short Bs[3][64][64];
    const int t = threadIdx.x;
    const int w = t >> 6, lane = t & 63, quad = lane >> 4, col = lane & 15;
    const int r0 = blockIdx.x * 128;
    const int c0 = blockIdx.y * 64;

    f32x4 acc[3][2][4] = {};

    for (int kk = 0; kk < D_MODEL; kk += 64) {
        __syncthreads();   // prior compute done reading LDS
        #pragma unroll
        for (int j = 0; j < 4; ++j) {
            int c = (w * 4 + j) * 64 + lane;
            async_ld16(xb + (size_t)(r0 + (c >> 3)) * D_MODEL + kk + (c & 7) * 8,
                       &As[0][0] + (size_t)c * 8);
        }
        #pragma unroll
        for (int z = 0; z < 3; ++z) {
            const unsigned short* Wt = wt + (size_t)z * D_MODEL * D_MODEL;
            #pragma unroll
            for (int j = 0; j < 2; ++j) {
                int c = (w * 2 + j) * 64 + lane;
                async_ld16(Wt + (size_t)(c0 + (c >> 3)) * D_MODEL + kk + (c & 7) * 8,
                           &Bs[z][0][0] + (size_t)c * 8);
            }
        }
        __syncthreads();   // DMA drained by pre-barrier vmcnt(0)
        #pragma unroll
        for (int ks = 0; ks < 2; ++ks) {
            short8 af[2];
            af[0] = *(const short8*)&As[w * 32 + col][ks * 32 + quad * 8];
            af[1] = *(const short8*)&As[w * 32 + 16 + col][ks * 32 + quad * 8];
            #pragma unroll
            for (int z = 0; z < 3; ++z) {
                short8 bf[4];
                #pragma unroll
                for (int nt = 0; nt < 4; ++nt)
                    bf[nt] = *(const short8*)&Bs[z][nt * 16 + col][ks * 32 + quad * 8];
                #pragma unroll
                for (int mt = 0; mt < 2; ++mt)
                    #pragma unroll
                    for (int nt = 0; nt < 4; ++nt)
                        acc[z][mt][nt] = __builtin_amdgcn_mfma_f32_16x16x32_bf16(
                            af[mt], bf[nt], acc[z][mt][nt], 0, 0, 0);
            }
        }
    }

    const int h = blockIdx.y;
    #pragma unroll
    for (int z = 0; z < 3; ++z) {
        const float* bias = (z == 0) ? bq : (z == 1) ? bk : bv;
        #pragma unroll
        for (int nt = 0; nt < 4; ++nt) {
            const float bv_ = bias[c0 + nt * 16 + col];
            const int hd = nt * 16 + col;
            #pragma unroll
            for (int mt = 0; mt < 2; ++mt) {
                #pragma unroll
                for (int reg = 0; reg < 4; ++reg) {
                    int r = r0 + w * 32 + mt * 16 + quad * 4 + reg;
                    int b = r >> 12, s = r & (SEQ - 1);
                    float val = acc[z][mt][nt][reg] + bv_;
                    size_t bh = (size_t)(b * NH + h);
                    size_t bhb = bh * (size_t)(SEQ * HD);
                    if (z == 0) {
                        qb[(bh * SEQ + s) * HD + hd] = f2bf(val * QSCALE);
                    } else if (z == 1) {
                        size_t idx = bhb + (size_t)(s >> 6) * 4096
                                   + (size_t)((s >> 5) & 1) * 2048
                                   + (size_t)(hd >> 4) * 512
                                   + (size_t)((hd >> 3) & 1) * 256
                                   + (size_t)(s & 31) * 8 + (hd & 7);
                        kb[idx] = f2bf(val);
                    } else {
                        size_t idx = bhb + (size_t)(s >> 6) * 4096
                                   + (size_t)(hd >> 5) * 2048
                                   + (size_t)((s >> 4) & 3) * 512
                                   + (size_t)((s >> 3) & 1) * 256
                                   + (size_t)(hd & 31) * 8 + (s & 7);
                        vtb[idx] = f2bf(val);
                    }
                }
            }
        }
    }
}

// ---------------------------------------------------------------------------
// Output projection: out = ab @ Wo + bo, fp32 out. R6 2-phase pipeline.
// ---------------------------------------------------------------------------
#define GEMM_STAGE(AS, BS, APTR, BPTR, KK)                                   \
    {                                                                        \
        _Pragma("unroll")                                                    \
        for (int j = 0; j < 4; ++j) {                                        \
            int c = (w * 4 + j) * 64 + lane;                                 \
            async_ld16(APTR + (size_t)(r0 + (c >> 3)) * D_MODEL + (KK) + (c & 7) * 8, \
                       &AS[0][0] + (size_t)c * 8);                           \
        }                                                                    \
        _Pragma("unroll")                                                    \
        for (int j = 0; j < 2; ++j) {                                        \
            int c = (w * 2 + j) * 64 + lane;                                 \
            async_ld16(BPTR + (size_t)(c0 + (c >> 3)) * D_MODEL + (KK) + (c & 7) * 8, \
                       &BS[0][0] + (size_t)c * 8);                           \
        }                                                                    \
    }

#define GEMM_COMPUTE(AS, BS)                                                 \
    {                                                                        \
        _Pragma("unroll")                                                    \
        for (int ks = 0; ks < 2; ++ks) {                                     \
            short8 af[2], bf[4];                                             \
            af[0] = *(const short8*)&AS[w * 32 + col][ks * 32 + quad * 8];   \
            af[1] = *(const short8*)&AS[w * 32 + 16 + col][ks * 32 + quad * 8]; \
            _Pragma("unroll")                                                \
            for (int nt = 0; nt < 4; ++nt)                                   \
                bf[nt] = *(const short8*)&BS[nt * 16 + col][ks * 32 + quad * 8]; \
            _Pragma("unroll")                                                \
            for (int mt = 0; mt < 2; ++mt)                                   \
                _Pragma("unroll")                                            \
                for (int nt = 0; nt < 4; ++nt)                               \
                    acc[mt][nt] = __builtin_amdgcn_mfma_f32_16x16x32_bf16(   \
                        af[mt], bf[nt], acc[mt][nt], 0, 0, 0);               \
        }                                                                    \
    }

__global__ __launch_bounds__(256) void out_mfma_k(
    const unsigned short* __restrict__ ab,
    const unsigned short* __restrict__ wot,
    const float* __restrict__ bo,
    float* __restrict__ out)
{
    __shared__ unsigned short As0[128][64], As1[128][64];
    __shared__ unsigned short Bs0[64][64],  Bs1[64][64];
    const int t = threadIdx.x;
    const int w = t >> 6, lane = t & 63, quad = lane >> 4, col = lane & 15;
    const int r0 = blockIdx.x * 128;
    const int c0 = blockIdx.y * 64;

    f32x4 acc[2][4] = {};

    GEMM_STAGE(As0, Bs0, ab, wot, 0);
    __syncthreads();
    #pragma unroll
    for (int kp = 0; kp < 6; ++kp) {
        GEMM_STAGE(As1, Bs1, ab, wot, kp * 128 + 64);
        GEMM_COMPUTE(As0, Bs0);
        __syncthreads();
        if (kp < 5) GEMM_STAGE(As0, Bs0, ab, wot, kp * 128 + 128);
        GEMM_COMPUTE(As1, Bs1);
        __syncthreads();
    }

    #pragma unroll
    for (int nt = 0; nt < 4; ++nt) {
        const float bv_ = bo[c0 + nt * 16 + col];
        #pragma unroll
        for (int mt = 0; mt < 2; ++mt) {
            #pragma unroll
            for (int reg = 0; reg < 4; ++reg) {
                int r = r0 + w * 32 + mt * 16 + quad * 4 + reg;
                out[(size_t)r * D_MODEL + c0 + nt * 16 + col] = acc[mt][nt][reg] + bv_;
            }
        }
    }
}

// register-only helper: exp2 + lsum tree + bf16 pack + hi/lo swap (R1 form)
__device__ __forceinline__ void softmax_pack(
    const f32x16& s, float& lsum, short8& pf0, short8& pf1)
{
    float p[16];
    #pragma unroll
    for (int r = 0; r < 16; ++r)
        p[r] = __builtin_amdgcn_exp2f(s[r]);
    lsum += (((p[0] + p[1]) + (p[2] + p[3])) + ((p[4] + p[5]) + (p[6] + p[7])))
          + (((p[8] + p[9]) + (p[10] + p[11])) + ((p[12] + p[13]) + (p[14] + p[15])));
    unsigned int c01 = cvtpk_bf16(p[0],  p[1]);
    unsigned int c45 = cvtpk_bf16(p[4],  p[5]);
    unsigned int c23 = cvtpk_bf16(p[2],  p[3]);
    unsigned int c67 = cvtpk_bf16(p[6],  p[7]);
    unsigned int c89 = cvtpk_bf16(p[8],  p[9]);
    unsigned int cCD = cvtpk_bf16(p[12], p[13]);
    unsigned int cAB = cvtpk_bf16(p[10], p[11]);
    unsigned int cEF = cvtpk_bf16(p[14], p[15]);
    auto r0 = __builtin_amdgcn_permlane32_swap((int)c01, (int)c45, false, false);
    auto r1 = __builtin_amdgcn_permlane32_swap((int)c23, (int)c67, false, false);
    auto r2 = __builtin_amdgcn_permlane32_swap((int)c89, (int)cCD, false, false);
    auto r3 = __builtin_amdgcn_permlane32_swap((int)cAB, (int)cEF, false, false);
    uint4v u0, u1;
    u0[0] = (unsigned int)r0[0]; u0[1] = (unsigned int)r1[0];
    u0[2] = (unsigned int)r0[1]; u0[3] = (unsigned int)r1[1];
    u1[0] = (unsigned int)r2[0]; u1[1] = (unsigned int)r3[0];
    u1[2] = (unsigned int)r2[1]; u1[3] = (unsigned int)r3[1];
    pf0 = u4_as_s8(u0);
    pf1 = u4_as_s8(u1);
}

// ---------------------------------------------------------------------------
// Flash attention (R12 champion — final): frag-tiled K/V + DMA double-buffer
// staging, ONE barrier/tile, sequential QK chains (interleaving regressed:
// R14), VALU lsum tree (ones-MFMA regressed: R10), 4 waves x 32 q.
// Structural attacks refuted this session: thin blocks (R3), split-K grid
// (R4/R5), global-direct (R8), in-block split-K (R9), ring-3 counted vmcnt
// (R13), chain interleave (R14). 138.7 us is this structure's floor.
// Block = (b, h, 128-q tile); 64-key tiles; grid 768 with XCD-chunked
// bijective swizzle (768 = 8*96).
// ---------------------------------------------------------------------------
__global__ __launch_bounds__(256) void flash_mfma_k(
    const unsigned short* __restrict__ qb,   // [B*NH][SEQ][64], pre-scaled
    const unsigned short* __restrict__ kb,   // frag-tiled
    const unsigned short* __restrict__ vtb,  // frag-tiled
    unsigned short* __restrict__ ab)         // [B][SEQ][768] bf16
{
    __shared__ unsigned short Ks[2][4096];
    __shared__ unsigned short Vts[2][4096];

    const int t = threadIdx.x;
    const int w = t >> 6, lane = t & 63;
    const int l31 = lane & 31, hi = lane >> 5;
    const int bid = blockIdx.x;
    const int lid = (bid & 7) * 96 + (bid >> 3);
    const int q0 = (lid & 31) * 128;
    const int hb = lid >> 5;                    // 0..23
    const int h = hb % NH, b = hb / NH;
    const size_t bh = (size_t)b * NH + h;
    const unsigned short* qg = qb + bh * SEQ * HD;
    const unsigned short* kgt = kb + bh * (size_t)(SEQ * HD);
    const unsigned short* vgt = vtb + bh * (size_t)(SEQ * HD);

    // persistent Q B-frags: q(n) = q0 + w*32 + l31, hd(k) = ks*16 + hi*8 + j
    short8 qf[4];
    {
        const unsigned short* src = qg + (size_t)(q0 + w * 32 + l31) * HD + hi * 8;
        #pragma unroll
        for (int ks = 0; ks < 4; ++ks)
            qf[ks] = *(const short8*)(src + ks * 16);
    }

    f32x16 oacc[2] = {};   // O^T [dt]: d = dt*32+(reg&3)+8*(reg>>2)+4*hi, q = l31
    float lsum = 0.f;

    // prologue: stage tile 0 into buf 0 (4 DMA per thread)
    #pragma unroll
    for (int j = 0; j < 2; ++j) {
        int c = w * 2 + j;
        async_ld16(kgt + (size_t)c * 512 + (size_t)lane * 8, &Ks[0][c * 512]);
        async_ld16(vgt + (size_t)c * 512 + (size_t)lane * 8, &Vts[0][c * 512]);
    }

    int buf = 0;
    for (int T = 0; T < SEQ / 64; ++T) {
        __syncthreads();   // drains buf's DMA (vmcnt0) + prior readers of buf^1
        if (T + 1 < SEQ / 64) {
            const size_t tb = (size_t)(T + 1) * 4096;
            int nb = buf ^ 1;
            #pragma unroll
            for (int j = 0; j < 2; ++j) {
                int c = w * 2 + j;
                async_ld16(kgt + tb + (size_t)c * 512 + (size_t)lane * 8,
                           &Ks[nb][c * 512]);
                async_ld16(vgt + tb + (size_t)c * 512 + (size_t)lane * 8,
                           &Vts[nb][c * 512]);
            }
        }

        // S^T = K Q^T; softmax + in-register P pack
        short8 pf[4];
        #pragma unroll
        for (int kti = 0; kti < 2; ++kti) {
            f32x16 s = {};
            __builtin_amdgcn_s_setprio(1);
            #pragma unroll
            for (int ks = 0; ks < 4; ++ks) {
                short8 kf = *(const short8*)&Ks[buf][(kti * 4 + ks) * 512 + lane * 8];
                s = __builtin_amdgcn_mfma_f32_32x32x16_bf16(kf, qf[ks], s, 0, 0, 0);
            }
            __builtin_amdgcn_s_setprio(0);
            softmax_pack(s, lsum, pf[kti * 2 + 0], pf[kti * 2 + 1]);
        }

        // PV: O^T = V^T P
        __builtin_amdgcn_s_setprio(1);
        #pragma unroll
        for (int ks = 0; ks < 4; ++ks) {
            short8 pfk = pf[ks];
            short8 vf0 = *(const short8*)&Vts[buf][ks * 512 + lane * 8];
            oacc[0] = __builtin_amdgcn_mfma_f32_32x32x16_bf16(vf0, pfk, oacc[0], 0, 0, 0);
            short8 vf1 = *(const short8*)&Vts[buf][(4 + ks) * 512 + lane * 8];
            oacc[1] = __builtin_amdgcn_mfma_f32_32x32x16_bf16(vf1, pfk, oacc[1], 0, 0, 0);
        }
        __builtin_amdgcn_s_setprio(0);
        buf ^= 1;
    }

    // epilogue: single cross-lane l reduction, normalize, b64 stores
    lsum += __shfl_xor(lsum, 32);
    float inv = 1.0f / lsum;
    int s = q0 + w * 32 + l31;
    unsigned short* dst = ab + ((size_t)b * SEQ + s) * D_MODEL + h * HD;
    #pragma unroll
    for (int dt = 0; dt < 2; ++dt) {
        #pragma unroll
        for (int rq = 0; rq < 4; ++rq) {
            short4v o4;
            o4[0] = (short)f2bf(oacc[dt][rq * 4 + 0] * inv);
            o4[1] = (short)f2bf(oacc[dt][rq * 4 + 1] * inv);
            o4[2] = (short)f2bf(oacc[dt][rq * 4 + 2] * inv);
            o4[3] = (short)f2bf(oacc[dt][rq * 4 + 3] * inv);
            *(short4v*)(dst + dt * 32 + rq * 8 + hi * 4) = o4;
        }
    }
}

extern "C" void kernel_launch(void* const* d_in, const int* in_sizes, int n_in,
                              void* d_out, int out_size, void* d_ws, size_t ws_size,
                              hipStream_t stream)
{
    const float* x  = (const float*)d_in[0];
    const float* Wq = (const float*)d_in[1];
    const float* bq = (const float*)d_in[2];
    const float* Wk = (const float*)d_in[3];
    const float* bk = (const float*)d_in[4];
    const float* Wv = (const float*)d_in[5];
    const float* bv = (const float*)d_in[6];
    const float* Wo = (const float*)d_in[7];
    const float* bo = (const float*)d_in[8];
    float* out = (float*)d_out;

    const size_t n_x  = (size_t)NROWS * D_MODEL;
    const size_t n_w  = (size_t)D_MODEL * D_MODEL;
    unsigned short* xb  = (unsigned short*)d_ws;
    unsigned short* wt  = xb + n_x;
    unsigned short* qb  = wt + 4 * n_w;
    unsigned short* kb  = qb + n_x;
    unsigned short* vtb = kb + n_x;
    unsigned short* ab  = vtb + n_x;
    const size_t need = ((size_t)5 * n_x + 4 * n_w) * sizeof(unsigned short);
    if (ws_size < need) return;

    convert_x_k<<<dim3((int)(n_x / 2048)), 256, 0, stream>>>(x, xb);
    convert_wt_k<<<dim3(12, 12, 4), 256, 0, stream>>>(Wq, Wk, Wv, Wo, wt);
    qkv_fused_k<<<dim3(NROWS / 128, D_MODEL / 64), 256, 0, stream>>>(
        xb, wt, bq, bk, bv, qb, kb, vtb);
    flash_mfma_k<<<dim3(SEQ / 128 * NH * BATCH), 256, 0, stream>>>(
        qb, kb, vtb, ab);
    out_mfma_k<<<dim3(NROWS / 128, D_MODEL / 64), 256, 0, stream>>>(
        ab, wt + 3 * n_w, bo, out);
}

// Round 16
// 277.510 us; speedup vs baseline: 1.0371x; 1.0371x over previous
//
#include <hip/hip_runtime.h>
#include <hip/hip_bf16.h>
#include <math.h>

#define D_MODEL 768
#define NH 12
#define HD 64
#define BATCH 2
#define SEQ 4096
#define NROWS (BATCH * SEQ)   // 8192

#define QSCALE 0.18033688011112042f   // 0.125 * log2(e): softmax via exp2

typedef __attribute__((ext_vector_type(8))) short short8;
typedef __attribute__((ext_vector_type(4))) short short4v;
typedef __attribute__((ext_vector_type(4))) float f32x4;
typedef __attribute__((ext_vector_type(16))) float f32x16;
typedef __attribute__((ext_vector_type(4))) unsigned int uint4v;

__device__ inline unsigned short f2bf(float f) {
    __hip_bfloat16 h = __float2bfloat16(f);   // RNE
    return *reinterpret_cast<unsigned short*>(&h);
}

// packed f32x2 -> bf16x2 (RNE), one VALU op
__device__ __forceinline__ unsigned int cvtpk_bf16(float lo, float hi) {
    unsigned int d;
    asm("v_cvt_pk_bf16_f32 %0, %1, %2" : "=v"(d) : "v"(lo), "v"(hi));
    return d;
}

__device__ __forceinline__ short8 u4_as_s8(uint4v u) {
    return *reinterpret_cast<short8*>(&u);
}

// async global->LDS DMA, 16 B per lane; LDS dest is wave-uniform base + lane*16
__device__ __forceinline__ void async_ld16(const unsigned short* g, unsigned short* l) {
    __builtin_amdgcn_global_load_lds(
        (const __attribute__((address_space(1))) void*)g,
        (__attribute__((address_space(3))) void*)l, 16, 0, 0);
}

// ---------------------------------------------------------------------------
// x fp32 -> bf16 (same layout). 8 elems/thread.
// ---------------------------------------------------------------------------
__global__ __launch_bounds__(256) void convert_x_k(
    const float* __restrict__ x, unsigned short* __restrict__ xb)
{
    size_t i = ((size_t)blockIdx.x * 256 + threadIdx.x) * 8;
    float4 a = *(const float4*)(x + i);
    float4 b = *(const float4*)(x + i + 4);
    short8 o;
    o[0] = (short)f2bf(a.x); o[1] = (short)f2bf(a.y);
    o[2] = (short)f2bf(a.z); o[3] = (short)f2bf(a.w);
    o[4] = (short)f2bf(b.x); o[5] = (short)f2bf(b.y);
    o[6] = (short)f2bf(b.z); o[7] = (short)f2bf(b.w);
    *(short8*)(xb + i) = o;
}

// ---------------------------------------------------------------------------
// W fp32 [768][768] -> Wt bf16 [768][768] TRANSPOSED (Wt[n][k] = W[k][n]).
// ---------------------------------------------------------------------------
__global__ __launch_bounds__(256) void convert_wt_k(
    const float* __restrict__ Wq, const float* __restrict__ Wk,
    const float* __restrict__ Wv, const float* __restrict__ Wo,
    unsigned short* __restrict__ wt)
{
    const float* W = (blockIdx.z == 0) ? Wq : (blockIdx.z == 1) ? Wk
                   : (blockIdx.z == 2) ? Wv : Wo;
    unsigned short* dst = wt + (size_t)blockIdx.z * D_MODEL * D_MODEL;
    __shared__ float tile[64][65];
    const int k0 = blockIdx.x * 64, n0 = blockIdx.y * 64;
    const int t = threadIdx.x;
    const int r = t >> 2, seg = t & 3;
    const float* src = W + (size_t)(k0 + r) * D_MODEL + n0 + seg * 16;
    #pragma unroll
    for (int i = 0; i < 4; ++i) {
        float4 v = *(const float4*)(src + i * 4);
        tile[r][seg * 16 + i * 4 + 0] = v.x;
        tile[r][seg * 16 + i * 4 + 1] = v.y;
        tile[r][seg * 16 + i * 4 + 2] = v.z;
        tile[r][seg * 16 + i * 4 + 3] = v.w;
    }
    __syncthreads();
    unsigned short* d = dst + (size_t)(n0 + r) * D_MODEL + k0 + seg * 16;
    short8 o0, o1;
    #pragma unroll
    for (int j = 0; j < 8; ++j) o0[j] = (short)f2bf(tile[seg * 16 + j][r]);
    #pragma unroll
    for (int j = 0; j < 8; ++j) o1[j] = (short)f2bf(tile[seg * 16 + 8 + j][r]);
    *(short8*)(d) = o0;
    *(short8*)(d + 8) = o1;
}

// ---------------------------------------------------------------------------
// FUSED QKV projection (R7 structure). K and V^T written in FRAG-TILED
// layouts so flash can stage/read MFMA fragments as linear 16B-per-lane
// chunks (also much better write coalescing for V^T — R10 measured win):
//   K tiled:  idx = bh*S*HD + T*4096 + kti*2048 + ks*512 + lane*8 + j
//   V tiled:  idx = bh*S*HD + T*4096 + dt*2048 + ks*512 + lane*8 + j
// ---------------------------------------------------------------------------
__global__ __launch_bounds__(256, 3) void qkv_fused_k(
    const unsigned short* __restrict__ xb,
    const unsigned short* __restrict__ wt,   // [3][768][768] (q,k,v transposed)
    const float* __restrict__ bq, const float* __restrict__ bk,
    const float* __restrict__ bv,
    unsigned short* __restrict__ qb,         // [B,H,S,64] (pre-scaled)
    unsigned short* __restrict__ kb,         // frag-tiled (see above)
    unsigned short* __restrict__ vtb)        // frag-tiled (see above)
{
    __shared__ unsigned short As[128][64];
    __shared__ unsigned short Bs[3][64][64];
    const int t = threadIdx.x;
    const int w = t >> 6, lane = t & 63, quad = lane >> 4, col = lane & 15;
    const int r0 = blockIdx.x * 128;
    const int c0 = blockIdx.y * 64;

    f32x4 acc[3][2][4] = {};

    for (int kk = 0; kk < D_MODEL; kk += 64) {
        __syncthreads();   // prior compute done reading LDS
        #pragma unroll
        for (int j = 0; j < 4; ++j) {
            int c = (w * 4 + j) * 64 + lane;
            async_ld16(xb + (size_t)(r0 + (c >> 3)) * D_MODEL + kk + (c & 7) * 8,
                       &As[0][0] + (size_t)c * 8);
        }
        #pragma unroll
        for (int z = 0; z < 3; ++z) {
            const unsigned short* Wt = wt + (size_t)z * D_MODEL * D_MODEL;
            #pragma unroll
            for (int j = 0; j < 2; ++j) {
                int c = (w * 2 + j) * 64 + lane;
                async_ld16(Wt + (size_t)(c0 + (c >> 3)) * D_MODEL + kk + (c & 7) * 8,
                           &Bs[z][0][0] + (size_t)c * 8);
            }
        }
        __syncthreads();   // DMA drained by pre-barrier vmcnt(0)
        #pragma unroll
        for (int ks = 0; ks < 2; ++ks) {
            short8 af[2];
            af[0] = *(const short8*)&As[w * 32 + col][ks * 32 + quad * 8];
            af[1] = *(const short8*)&As[w * 32 + 16 + col][ks * 32 + quad * 8];
            #pragma unroll
            for (int z = 0; z < 3; ++z) {
                short8 bf[4];
                #pragma unroll
                for (int nt = 0; nt < 4; ++nt)
                    bf[nt] = *(const short8*)&Bs[z][nt * 16 + col][ks * 32 + quad * 8];
                #pragma unroll
                for (int mt = 0; mt < 2; ++mt)
                    #pragma unroll
                    for (int nt = 0; nt < 4; ++nt)
                        acc[z][mt][nt] = __builtin_amdgcn_mfma_f32_16x16x32_bf16(
                            af[mt], bf[nt], acc[z][mt][nt], 0, 0, 0);
            }
        }
    }

    const int h = blockIdx.y;
    #pragma unroll
    for (int z = 0; z < 3; ++z) {
        const float* bias = (z == 0) ? bq : (z == 1) ? bk : bv;
        #pragma unroll
        for (int nt = 0; nt < 4; ++nt) {
            const float bv_ = bias[c0 + nt * 16 + col];
            const int hd = nt * 16 + col;
            #pragma unroll
            for (int mt = 0; mt < 2; ++mt) {
                #pragma unroll
                for (int reg = 0; reg < 4; ++reg) {
                    int r = r0 + w * 32 + mt * 16 + quad * 4 + reg;
                    int b = r >> 12, s = r & (SEQ - 1);
                    float val = acc[z][mt][nt][reg] + bv_;
                    size_t bh = (size_t)(b * NH + h);
                    size_t bhb = bh * (size_t)(SEQ * HD);
                    if (z == 0) {
                        qb[(bh * SEQ + s) * HD + hd] = f2bf(val * QSCALE);
                    } else if (z == 1) {
                        size_t idx = bhb + (size_t)(s >> 6) * 4096
                                   + (size_t)((s >> 5) & 1) * 2048
                                   + (size_t)(hd >> 4) * 512
                                   + (size_t)((hd >> 3) & 1) * 256
                                   + (size_t)(s & 31) * 8 + (hd & 7);
                        kb[idx] = f2bf(val);
                    } else {
                        size_t idx = bhb + (size_t)(s >> 6) * 4096
                                   + (size_t)(hd >> 5) * 2048
                                   + (size_t)((s >> 4) & 3) * 512
                                   + (size_t)((s >> 3) & 1) * 256
                                   + (size_t)(hd & 31) * 8 + (s & 7);
                        vtb[idx] = f2bf(val);
                    }
                }
            }
        }
    }
}

// ---------------------------------------------------------------------------
// Output projection: out = ab @ Wo + bo, fp32 out. R6 2-phase pipeline.
// ---------------------------------------------------------------------------
#define GEMM_STAGE(AS, BS, APTR, BPTR, KK)                                   \
    {                                                                        \
        _Pragma("unroll")                                                    \
        for (int j = 0; j < 4; ++j) {                                        \
            int c = (w * 4 + j) * 64 + lane;                                 \
            async_ld16(APTR + (size_t)(r0 + (c >> 3)) * D_MODEL + (KK) + (c & 7) * 8, \
                       &AS[0][0] + (size_t)c * 8);                           \
        }                                                                    \
        _Pragma("unroll")                                                    \
        for (int j = 0; j < 2; ++j) {                                        \
            int c = (w * 2 + j) * 64 + lane;                                 \
            async_ld16(BPTR + (size_t)(c0 + (c >> 3)) * D_MODEL + (KK) + (c & 7) * 8, \
                       &BS[0][0] + (size_t)c * 8);                           \
        }                                                                    \
    }

#define GEMM_COMPUTE(AS, BS)                                                 \
    {                                                                        \
        _Pragma("unroll")                                                    \
        for (int ks = 0; ks < 2; ++ks) {                                     \
            short8 af[2], bf[4];                                             \
            af[0] = *(const short8*)&AS[w * 32 + col][ks * 32 + quad * 8];   \
            af[1] = *(const short8*)&AS[w * 32 + 16 + col][ks * 32 + quad * 8]; \
            _Pragma("unroll")                                                \
            for (int nt = 0; nt < 4; ++nt)                                   \
                bf[nt] = *(const short8*)&BS[nt * 16 + col][ks * 32 + quad * 8]; \
            _Pragma("unroll")                                                \
            for (int mt = 0; mt < 2; ++mt)                                   \
                _Pragma("unroll")                                            \
                for (int nt = 0; nt < 4; ++nt)                               \
                    acc[mt][nt] = __builtin_amdgcn_mfma_f32_16x16x32_bf16(   \
                        af[mt], bf[nt], acc[mt][nt], 0, 0, 0);               \
        }                                                                    \
    }

__global__ __launch_bounds__(256) void out_mfma_k(
    const unsigned short* __restrict__ ab,
    const unsigned short* __restrict__ wot,
    const float* __restrict__ bo,
    float* __restrict__ out)
{
    __shared__ unsigned short As0[128][64], As1[128][64];
    __shared__ unsigned short Bs0[64][64],  Bs1[64][64];
    const int t = threadIdx.x;
    const int w = t >> 6, lane = t & 63, quad = lane >> 4, col = lane & 15;
    const int r0 = blockIdx.x * 128;
    const int c0 = blockIdx.y * 64;

    f32x4 acc[2][4] = {};

    GEMM_STAGE(As0, Bs0, ab, wot, 0);
    __syncthreads();
    #pragma unroll
    for (int kp = 0; kp < 6; ++kp) {
        GEMM_STAGE(As1, Bs1, ab, wot, kp * 128 + 64);
        GEMM_COMPUTE(As0, Bs0);
        __syncthreads();
        if (kp < 5) GEMM_STAGE(As0, Bs0, ab, wot, kp * 128 + 128);
        GEMM_COMPUTE(As1, Bs1);
        __syncthreads();
    }

    #pragma unroll
    for (int nt = 0; nt < 4; ++nt) {
        const float bv_ = bo[c0 + nt * 16 + col];
        #pragma unroll
        for (int mt = 0; mt < 2; ++mt) {
            #pragma unroll
            for (int reg = 0; reg < 4; ++reg) {
                int r = r0 + w * 32 + mt * 16 + quad * 4 + reg;
                out[(size_t)r * D_MODEL + c0 + nt * 16 + col] = acc[mt][nt][reg] + bv_;
            }
        }
    }
}

// register-only helper: exp2 + lsum tree + bf16 pack + hi/lo swap (R1 form)
__device__ __forceinline__ void softmax_pack(
    const f32x16& s, float& lsum, short8& pf0, short8& pf1)
{
    float p[16];
    #pragma unroll
    for (int r = 0; r < 16; ++r)
        p[r] = __builtin_amdgcn_exp2f(s[r]);
    lsum += (((p[0] + p[1]) + (p[2] + p[3])) + ((p[4] + p[5]) + (p[6] + p[7])))
          + (((p[8] + p[9]) + (p[10] + p[11])) + ((p[12] + p[13]) + (p[14] + p[15])));
    unsigned int c01 = cvtpk_bf16(p[0],  p[1]);
    unsigned int c45 = cvtpk_bf16(p[4],  p[5]);
    unsigned int c23 = cvtpk_bf16(p[2],  p[3]);
    unsigned int c67 = cvtpk_bf16(p[6],  p[7]);
    unsigned int c89 = cvtpk_bf16(p[8],  p[9]);
    unsigned int cCD = cvtpk_bf16(p[12], p[13]);
    unsigned int cAB = cvtpk_bf16(p[10], p[11]);
    unsigned int cEF = cvtpk_bf16(p[14], p[15]);
    auto r0 = __builtin_amdgcn_permlane32_swap((int)c01, (int)c45, false, false);
    auto r1 = __builtin_amdgcn_permlane32_swap((int)c23, (int)c67, false, false);
    auto r2 = __builtin_amdgcn_permlane32_swap((int)c89, (int)cCD, false, false);
    auto r3 = __builtin_amdgcn_permlane32_swap((int)cAB, (int)cEF, false, false);
    uint4v u0, u1;
    u0[0] = (unsigned int)r0[0]; u0[1] = (unsigned int)r1[0];
    u0[2] = (unsigned int)r0[1]; u0[3] = (unsigned int)r1[1];
    u1[0] = (unsigned int)r2[0]; u1[1] = (unsigned int)r3[0];
    u1[2] = (unsigned int)r2[1]; u1[3] = (unsigned int)r3[1];
    pf0 = u4_as_s8(u0);
    pf1 = u4_as_s8(u1);
}

// ---------------------------------------------------------------------------
// Flash attention R16: frag-tiled layouts (qkv-epilogue win, R10) combined
// with the REG-STAGED loop shape (R6/R7, consistently ~4 us faster than the
// DMA-staged loop R11/R12/R15: bursty LDS writes at the barrier instead of
// DMA trickling into LDS mid-compute contending with ds_reads).
// Single-buffered LDS (16 KB), 2 barriers/tile, T14 register prefetch.
// Linear frag-tiled chunks: conflict-free LDS without padding; coalesced
// 1KB-per-wave global reads. XCD-chunked bijective swizzle (768 = 8*96).
// Sequential QK chains (interleave regressed R14), VALU lsum (ones-MFMA
// regressed R10). Block = (b, h, 128-q tile); 4 waves x 32 q.
// ---------------------------------------------------------------------------
__global__ __launch_bounds__(256) void flash_mfma_k(
    const unsigned short* __restrict__ qb,   // [B*NH][SEQ][64], pre-scaled
    const unsigned short* __restrict__ kb,   // frag-tiled
    const unsigned short* __restrict__ vtb,  // frag-tiled
    unsigned short* __restrict__ ab)         // [B][SEQ][768] bf16
{
    __shared__ unsigned short Ks[4096];
    __shared__ unsigned short Vts[4096];

    const int t = threadIdx.x;
    const int w = t >> 6, lane = t & 63;
    const int l31 = lane & 31, hi = lane >> 5;
    const int bid = blockIdx.x;
    const int lid = (bid & 7) * 96 + (bid >> 3);
    const int q0 = (lid & 31) * 128;
    const int hb = lid >> 5;                    // 0..23
    const int h = hb % NH, b = hb / NH;
    const size_t bh = (size_t)b * NH + h;
    const unsigned short* qg = qb + bh * SEQ * HD;
    const unsigned short* kgt = kb + bh * (size_t)(SEQ * HD);
    const unsigned short* vgt = vtb + bh * (size_t)(SEQ * HD);

    // persistent Q B-frags: q(n) = q0 + w*32 + l31, hd(k) = ks*16 + hi*8 + j
    short8 qf[4];
    {
        const unsigned short* src = qg + (size_t)(q0 + w * 32 + l31) * HD + hi * 8;
        #pragma unroll
        for (int ks = 0; ks < 4; ++ks)
            qf[ks] = *(const short8*)(src + ks * 16);
    }

    f32x16 oacc[2] = {};   // O^T [dt]: d = dt*32+(reg&3)+8*(reg>>2)+4*hi, q = l31
    float lsum = 0.f;
    const int c0 = w * 2, c1 = w * 2 + 1;      // this thread's two chunks

    // prologue prefetch: tile 0 into registers (2 chunks K + 2 chunks V)
    short8 kr0, kr1, vr0, vr1;
    {
        kr0 = *(const short8*)(kgt + (size_t)c0 * 512 + (size_t)lane * 8);
        kr1 = *(const short8*)(kgt + (size_t)c1 * 512 + (size_t)lane * 8);
        vr0 = *(const short8*)(vgt + (size_t)c0 * 512 + (size_t)lane * 8);
        vr1 = *(const short8*)(vgt + (size_t)c1 * 512 + (size_t)lane * 8);
    }

    for (int T = 0; T < SEQ / 64; ++T) {
        __syncthreads();   // prior compute done reading LDS
        *(short8*)&Ks[c0 * 512 + lane * 8]  = kr0;
        *(short8*)&Ks[c1 * 512 + lane * 8]  = kr1;
        *(short8*)&Vts[c0 * 512 + lane * 8] = vr0;
        *(short8*)&Vts[c1 * 512 + lane * 8] = vr1;
        // T14: issue next tile's loads now; latency hides under compute below
        if (T + 1 < SEQ / 64) {
            const size_t tb = (size_t)(T + 1) * 4096;
            kr0 = *(const short8*)(kgt + tb + (size_t)c0 * 512 + (size_t)lane * 8);
            kr1 = *(const short8*)(kgt + tb + (size_t)c1 * 512 + (size_t)lane * 8);
            vr0 = *(const short8*)(vgt + tb + (size_t)c0 * 512 + (size_t)lane * 8);
            vr1 = *(const short8*)(vgt + tb + (size_t)c1 * 512 + (size_t)lane * 8);
        }
        __syncthreads();   // staged tile visible to all waves

        // S^T = K Q^T; softmax + in-register P pack
        short8 pf[4];
        #pragma unroll
        for (int kti = 0; kti < 2; ++kti) {
            f32x16 s = {};
            __builtin_amdgcn_s_setprio(1);
            #pragma unroll
            for (int ks = 0; ks < 4; ++ks) {
                short8 kf = *(const short8*)&Ks[(kti * 4 + ks) * 512 + lane * 8];
                s = __builtin_amdgcn_mfma_f32_32x32x16_bf16(kf, qf[ks], s, 0, 0, 0);
            }
            __builtin_amdgcn_s_setprio(0);
            softmax_pack(s, lsum, pf[kti * 2 + 0], pf[kti * 2 + 1]);
        }

        // PV: O^T = V^T P
        __builtin_amdgcn_s_setprio(1);
        #pragma unroll
        for (int ks = 0; ks < 4; ++ks) {
            short8 pfk = pf[ks];
            short8 vf0 = *(const short8*)&Vts[ks * 512 + lane * 8];
            oacc[0] = __builtin_amdgcn_mfma_f32_32x32x16_bf16(vf0, pfk, oacc[0], 0, 0, 0);
            short8 vf1 = *(const short8*)&Vts[(4 + ks) * 512 + lane * 8];
            oacc[1] = __builtin_amdgcn_mfma_f32_32x32x16_bf16(vf1, pfk, oacc[1], 0, 0, 0);
        }
        __builtin_amdgcn_s_setprio(0);
    }

    // epilogue: single cross-lane l reduction, normalize, b64 stores
    lsum += __shfl_xor(lsum, 32);
    float inv = 1.0f / lsum;
    int s = q0 + w * 32 + l31;
    unsigned short* dst = ab + ((size_t)b * SEQ + s) * D_MODEL + h * HD;
    #pragma unroll
    for (int dt = 0; dt < 2; ++dt) {
        #pragma unroll
        for (int rq = 0; rq < 4; ++rq) {
            short4v o4;
            o4[0] = (short)f2bf(oacc[dt][rq * 4 + 0] * inv);
            o4[1] = (short)f2bf(oacc[dt][rq * 4 + 1] * inv);
            o4[2] = (short)f2bf(oacc[dt][rq * 4 + 2] * inv);
            o4[3] = (short)f2bf(oacc[dt][rq * 4 + 3] * inv);
            *(short4v*)(dst + dt * 32 + rq * 8 + hi * 4) = o4;
        }
    }
}

extern "C" void kernel_launch(void* const* d_in, const int* in_sizes, int n_in,
                              void* d_out, int out_size, void* d_ws, size_t ws_size,
                              hipStream_t stream)
{
    const float* x  = (const float*)d_in[0];
    const float* Wq = (const float*)d_in[1];
    const float* bq = (const float*)d_in[2];
    const float* Wk = (const float*)d_in[3];
    const float* bk = (const float*)d_in[4];
    const float* Wv = (const float*)d_in[5];
    const float* bv = (const float*)d_in[6];
    const float* Wo = (const float*)d_in[7];
    const float* bo = (const float*)d_in[8];
    float* out = (float*)d_out;

    const size_t n_x  = (size_t)NROWS * D_MODEL;
    const size_t n_w  = (size_t)D_MODEL * D_MODEL;
    unsigned short* xb  = (unsigned short*)d_ws;
    unsigned short* wt  = xb + n_x;
    unsigned short* qb  = wt + 4 * n_w;
    unsigned short* kb  = qb + n_x;
    unsigned short* vtb = kb + n_x;
    unsigned short* ab  = vtb + n_x;
    const size_t need = ((size_t)5 * n_x + 4 * n_w) * sizeof(unsigned short);
    if (ws_size < need) return;

    convert_x_k<<<dim3((int)(n_x / 2048)), 256, 0, stream>>>(x, xb);
    convert_wt_k<<<dim3(12, 12, 4), 256, 0, stream>>>(Wq, Wk, Wv, Wo, wt);
    qkv_fused_k<<<dim3(NROWS / 128, D_MODEL / 64), 256, 0, stream>>>(
        xb, wt, bq, bk, bv, qb, kb, vtb);
    flash_mfma_k<<<dim3(SEQ / 128 * NH * BATCH), 256, 0, stream>>>(
        qb, kb, vtb, ab);
    out_mfma_k<<<dim3(NROWS / 128, D_MODEL / 64), 256, 0, stream>>>(
        ab, wt + 3 * n_w, bo, out);
}